// Round 1
// 1553.343 us; speedup vs baseline: 1.1393x; 1.1393x over previous
//
#include <hip/hip_runtime.h>
#include <math.h>

#define NSTEPS 50
#define NHID   64
#define NFEAT  11

// tanh(x) = 1 - 2/(e^{2x}+1); v_exp + v_rcp, ~3e-7 abs err (absorbed by fp32
// state quantization: delta_corr*DT << ulp(v) -> no trajectory divergence).
__device__ __forceinline__ float fast_tanh(float x) {
    float e = __expf(x + x);                       // inf for large x -> rcp->0 -> +1; 0 for very neg -> -1
    return 1.0f - 2.0f * __builtin_amdgcn_rcpf(e + 1.0f);
}

__global__ __launch_bounds__(256, 2)
void phys_mlp_kernel(const float* __restrict__ inputs,
                     const float* __restrict__ W1,
                     const float* __restrict__ b1,
                     const float* __restrict__ W2,
                     const float* __restrict__ b2,
                     const float* __restrict__ W3,
                     const float* __restrict__ b3,
                     const float* __restrict__ grav,
                     const float* __restrict__ fric,
                     float* __restrict__ out,
                     int nb) {
    // W2^T staged in LDS: the 16 KB weight stream was thrashing the scalar L1
    // every step (20 KB scalar working set). LDS reads are uniform-address ->
    // broadcast, conflict-free, always on-chip. W1/b/W3 (~3 KB) stay on the
    // s_load path, which now fits sL1.
    __shared__ __attribute__((aligned(16))) float sW2T[NHID * NHID];

    // stage + transpose once per block (49 steps amortize; reads hit L2/L3)
    for (int i = threadIdx.x; i < NHID * NHID; i += 256)
        sW2T[i] = W2[((i & 63) << 6) | (i >> 6)];  // sW2T[j*64+k] = W2[k*64+j]
    __syncthreads();

    int b = blockIdx.x * blockDim.x + threadIdx.x;
    if (b >= nb) return;

    const float DTF = 1.0f / 30.0f;                // == float(1/30) used by np reference
    float pg = __fmul_rn(grav[0], 40.0f);          // pixel_gravity
    float fr = fabsf(fric[0]);

    // state = inputs[b, 0, :]  (only t=0 of the input trajectory is used)
    const float4* in4 = (const float4*)(inputs + (size_t)b * NSTEPS * 8);
    float4 s0 = in4[0], s1 = in4[1];
    float p1x = s0.x, p1y = s0.y, p2x = s0.z, p2y = s0.w;
    float v1x = s1.x, v1y = s1.y, v2x = s1.z, v2y = s1.w;

    float4* o4 = (float4*)(out + (size_t)b * NSTEPS * 8);

    #pragma unroll 1
    for (int t = 0; t < NSTEPS; ++t) {
        // scan collects the PRE-step state: out[b,0] = initial state (bit-exact copy)
        o4[0] = make_float4(p1x, p1y, p2x, p2y);
        o4[1] = make_float4(v1x, v1y, v2x, v2y);
        o4 += 2;
        if (t == NSTEPS - 1) break;                // 50th update is discarded by scan

        // ---------------- features (np op order, no contraction) ----------------
        float feats[NFEAT];
        {
            float r = __fsqrt_rn(__fadd_rn(__fmul_rn(p1x, p1x), __fmul_rn(p1y, p1y)));
            feats[0] = r;
            feats[1] = atan2f(p1y, p1x);
            feats[2] = __fdiv_rn(__fadd_rn(__fmul_rn(p1x, v1x), __fmul_rn(p1y, v1y)),
                                 __fadd_rn(r, 1e-6f));
            float vt = __fdiv_rn(__fsub_rn(__fmul_rn(p1x, v1y), __fmul_rn(p1y, v1x)),
                                 __fadd_rn(__fmul_rn(r, r), 1e-6f));
            feats[3] = vt;
            feats[4] = __fmul_rn(r, vt);
        }
        {
            float r = __fsqrt_rn(__fadd_rn(__fmul_rn(p2x, p2x), __fmul_rn(p2y, p2y)));
            feats[5] = r;
            feats[6] = atan2f(p2y, p2x);
            feats[7] = __fdiv_rn(__fadd_rn(__fmul_rn(p2x, v2x), __fmul_rn(p2y, v2y)),
                                 __fadd_rn(r, 1e-6f));
            float vt = __fdiv_rn(__fsub_rn(__fmul_rn(p2x, v2y), __fmul_rn(p2y, v2x)),
                                 __fadd_rn(__fmul_rn(r, r), 1e-6f));
            feats[8] = vt;
            feats[9] = __fmul_rn(r, vt);
        }
        {
            float dx = __fsub_rn(p2x, p1x), dy = __fsub_rn(p2y, p1y);
            feats[10] = __fsqrt_rn(__fadd_rn(__fmul_rn(dx, dx), __fmul_rn(dy, dy)));
        }

        // ---------------- layer 1: 11 -> 64, fully unrolled (feats/h1 stay in VGPRs,
        // W1 rows contiguous + wave-uniform addresses -> s_load, fits sL1 now) ------
        float h1[NHID];
        #pragma unroll
        for (int j = 0; j < NHID; ++j) h1[j] = b1[j];
        #pragma unroll
        for (int k = 0; k < NFEAT; ++k) {
            float f = feats[k];
            #pragma unroll
            for (int j = 0; j < NHID; ++j)
                h1[j] = fmaf(f, W1[k * NHID + j], h1[j]);
        }
        #pragma unroll
        for (int j = 0; j < NHID; ++j) h1[j] = fast_tanh(h1[j]);

        // ---------------- layer 2 (64->64) fused with layer 3 (64->2) ------------
        // j-loop rolled (keeps LDS loads j-dependent -> not LICM-hoistable),
        // k-loop unrolled (h1[k] const-indexed -> regs), 4 independent FMA chains,
        // weights via uniform-address ds_read_b128 broadcast (conflict-free).
        // FMA accumulation order identical to previous kernel: k ascending per chain.
        float c0 = b3[0], c1 = b3[1];
        #pragma unroll 1
        for (int j = 0; j < NHID; j += 4) {
            const float4* __restrict__ w0 = (const float4*)(sW2T + (j << 6));
            const float4* __restrict__ w1 = w0 + (NHID / 4);
            const float4* __restrict__ w2 = w1 + (NHID / 4);
            const float4* __restrict__ w3 = w2 + (NHID / 4);
            float a0 = b2[j], a1 = b2[j + 1], a2 = b2[j + 2], a3 = b2[j + 3];
            #pragma unroll
            for (int q = 0; q < NHID / 4; ++q) {
                float4 q0 = w0[q], q1 = w1[q], q2 = w2[q], q3 = w3[q];
                float h0 = h1[4 * q], hA = h1[4 * q + 1];
                float hB = h1[4 * q + 2], hC = h1[4 * q + 3];
                a0 = fmaf(h0, q0.x, a0); a0 = fmaf(hA, q0.y, a0);
                a0 = fmaf(hB, q0.z, a0); a0 = fmaf(hC, q0.w, a0);
                a1 = fmaf(h0, q1.x, a1); a1 = fmaf(hA, q1.y, a1);
                a1 = fmaf(hB, q1.z, a1); a1 = fmaf(hC, q1.w, a1);
                a2 = fmaf(h0, q2.x, a2); a2 = fmaf(hA, q2.y, a2);
                a2 = fmaf(hB, q2.z, a2); a2 = fmaf(hC, q2.w, a2);
                a3 = fmaf(h0, q3.x, a3); a3 = fmaf(hA, q3.y, a3);
                a3 = fmaf(hB, q3.z, a3); a3 = fmaf(hC, q3.w, a3);
            }
            float t0 = fast_tanh(a0), t1 = fast_tanh(a1);
            float t2 = fast_tanh(a2), t3 = fast_tanh(a3);
            c0 = fmaf(t0, W3[(j + 0) * 2], c0);  c1 = fmaf(t0, W3[(j + 0) * 2 + 1], c1);
            c0 = fmaf(t1, W3[(j + 1) * 2], c0);  c1 = fmaf(t1, W3[(j + 1) * 2 + 1], c1);
            c0 = fmaf(t2, W3[(j + 2) * 2], c0);  c1 = fmaf(t2, W3[(j + 2) * 2 + 1], c1);
            c0 = fmaf(t3, W3[(j + 3) * 2], c0);  c1 = fmaf(t3, W3[(j + 3) * 2 + 1], c1);
        }
        float corr0 = __fmul_rn(c0, 0.1f);
        float corr1 = __fmul_rn(c1, 0.1f);

        // ---------------- integrate (MUST be non-fused, np op order) -------------
        float ax1 = __fadd_rn(__fsub_rn(0.0f, __fmul_rn(fr, v1x)), corr0);
        float ay1 = __fadd_rn(__fsub_rn(pg,   __fmul_rn(fr, v1y)), corr1);
        float ax2 = __fadd_rn(__fsub_rn(0.0f, __fmul_rn(fr, v2x)), corr0);
        float ay2 = __fadd_rn(__fsub_rn(pg,   __fmul_rn(fr, v2y)), corr1);
        float nv1x = __fadd_rn(v1x, __fmul_rn(ax1, DTF));
        float nv1y = __fadd_rn(v1y, __fmul_rn(ay1, DTF));
        float nv2x = __fadd_rn(v2x, __fmul_rn(ax2, DTF));
        float nv2y = __fadd_rn(v2y, __fmul_rn(ay2, DTF));
        float np1x = __fadd_rn(p1x, __fmul_rn(nv1x, DTF));
        float np1y = __fadd_rn(p1y, __fmul_rn(nv1y, DTF));
        float np2x = __fadd_rn(p2x, __fmul_rn(nv2x, DTF));
        float np2y = __fadd_rn(p2y, __fmul_rn(nv2y, DTF));

        // ---------------- bounce (mask on pre-clip pos; clip is min(max(.))) -----
        nv1x = (np1x < 20.0f || np1x > 780.0f) ? __fmul_rn(-0.8f, nv1x) : nv1x;
        np1x = fminf(fmaxf(np1x, 20.0f), 780.0f);
        nv1y = (np1y < 20.0f || np1y > 580.0f) ? __fmul_rn(-0.8f, nv1y) : nv1y;
        np1y = fminf(fmaxf(np1y, 20.0f), 580.0f);
        nv2x = (np2x < 20.0f || np2x > 780.0f) ? __fmul_rn(-0.8f, nv2x) : nv2x;
        np2x = fminf(fmaxf(np2x, 20.0f), 780.0f);
        nv2y = (np2y < 20.0f || np2y > 580.0f) ? __fmul_rn(-0.8f, nv2y) : nv2y;
        np2y = fminf(fmaxf(np2y, 20.0f), 580.0f);

        p1x = np1x; p1y = np1y; p2x = np2x; p2y = np2y;
        v1x = nv1x; v1y = nv1y; v2x = nv2x; v2y = nv2y;
    }
}

extern "C" void kernel_launch(void* const* d_in, const int* in_sizes, int n_in,
                              void* d_out, int out_size, void* d_ws, size_t ws_size,
                              hipStream_t stream) {
    const float* inputs = (const float*)d_in[0];
    const float* W1     = (const float*)d_in[1];
    const float* b1     = (const float*)d_in[2];
    const float* W2     = (const float*)d_in[3];
    const float* b2     = (const float*)d_in[4];
    const float* W3     = (const float*)d_in[5];
    const float* b3     = (const float*)d_in[6];
    const float* grav   = (const float*)d_in[7];
    const float* fric   = (const float*)d_in[8];
    float* out = (float*)d_out;
    (void)d_ws; (void)ws_size;

    int nb = in_sizes[0] / (NSTEPS * 8);
    int blocks = (nb + 255) / 256;
    phys_mlp_kernel<<<blocks, 256, 0, stream>>>(inputs, W1, b1, W2, b2, W3, b3,
                                                grav, fric, out, nb);
}